// Round 9
// baseline (349.475 us; speedup 1.0000x reference)
//
#include <hip/hip_runtime.h>
#include <cstdint>
#include <cstddef>

typedef __attribute__((ext_vector_type(8))) __bf16 bf16x8;
typedef __attribute__((ext_vector_type(16))) float floatx16;

struct SrcPtrs { const float* p[9]; };

// ---------------- weight workspace layout (bf16 elems) ----------------
// Frag-major per layer: frag f = t*S + s (t = 32-feature tile, s = 16-k step).
// Each frag = 1024 B = 64 lanes x 16 B; lane l = q2*32 + l31 holds
// row (32t + l31), k = 16s + 8*q2 + {0..7} — the 32x32x16 bf16 A layout.
// r7: the k index additionally carries the involution phi = swap bits 2,3 of
// (k & 15). With phi baked into the stored weights AND the trig feature
// mapping, the packed C-output registers of layer L are BIT-IDENTICAL to the
// B-fragments of layer L+1 -> no cross-lane half-swap, no B-build.
// m  mat    K    Nout  S   NT  off(shorts)  remap
// 0  Wd1_0  60   128   4   4   0
// 1  Wd1_1  128  128   8   4   8192
// 2  Wd1_2  128  128   8   4   24576
// 3  Wd2_0  188  128   12  4   40960    k<60 -> 128+k, k>=60 -> k-60
// 4  Wd2_1  128  128   8   4   65536
// 5  Wd2_2  128  128   8   4   81920
// 6  Wd2_3  128  129   8   5   98304    col0 -> row128 (blend), col j+1 -> row j
// 7  Wc_0   152  128   10  4   118784   k<24 -> 128+k, k>=24 -> k-24
// 8  Wc_1   128  3     8   1   139264   rows 3..31 zero
// total 143360 shorts = 286720 B

__global__ void prep_zero(unsigned short* __restrict__ ws) {
  uint4* p = (uint4*)ws;
  const int n = 143360 / 8;
  for (int i = blockIdx.x * blockDim.x + threadIdx.x; i < n; i += gridDim.x * blockDim.x)
    p[i] = make_uint4(0u, 0u, 0u, 0u);
}

__global__ void prep_fill(SrcPtrs sp, unsigned short* __restrict__ ws) {
  const int m  = blockIdx.x >> 4;
  const int sl = blockIdx.x & 15;
  const int K[9]  = {60, 128, 128, 188, 128, 128, 128, 152, 128};
  const int N[9]  = {128, 128, 128, 128, 128, 128, 129, 128, 3};
  const int SS[9] = {4, 8, 8, 12, 8, 8, 8, 10, 8};
  const unsigned OFF[9] = {0u, 8192u, 24576u, 40960u, 65536u, 81920u, 98304u, 118784u, 139264u};
  const int Km = K[m], Nm = N[m], Sm = SS[m];
  const float* __restrict__ src = sp.p[m];
  unsigned short* __restrict__ dst = ws + OFF[m];
  const int tot = Km * Nm;
  for (int i = sl * 256 + (int)threadIdx.x; i < tot; i += 16 * 256) {
    int k = i / Nm;
    int n = i - k * Nm;
    int kk = k, row = n;
    if (m == 3) kk = (k < 60) ? 128 + k : k - 60;
    if (m == 7) kk = (k < 24) ? 128 + k : k - 24;
    if (m == 6) row = (n == 0) ? 128 : n - 1;
    // phi: swap bits 2,3 of the k low nibble (involution). Makes packed
    // C-outputs feed MFMA-B directly (see header comment).
    kk = (kk & ~12) | (((kk & 4) << 1) | ((kk & 8) >> 1));
    const int t = row >> 5, l31 = row & 31;
    const int s = kk >> 4, q2 = (kk >> 3) & 1, j = kk & 7;
    dst[(t * Sm + s) * 512 + (q2 * 32 + l31) * 8 + j] =
        __builtin_bit_cast(unsigned short, (__bf16)src[i]);
  }
}

// ---------------- main fused kernel ----------------

__device__ __forceinline__ unsigned pk2(float a, float b) {
  unsigned short ua = __builtin_bit_cast(unsigned short, (__bf16)a);
  unsigned short ub = __builtin_bit_cast(unsigned short, (__bf16)b);
  return (unsigned)ua | ((unsigned)ub << 16);
}

__device__ __forceinline__ void stage16(const void* g, void* l) {
  __builtin_amdgcn_global_load_lds(
      (const __attribute__((address_space(1))) unsigned int*)g,
      (__attribute__((address_space(3))) unsigned int*)l, 16, 0, 0);
}

// sin/cos of v * pi * 2^f == sin/cos(2*pi*rev), rev = v * 2^(f-1) (HW revolutions)
// phi-adjusted feature mapping: lane q2, element j supplies feature
// f = 16*sl + j + 4*q2 + (j>=4 ? 4 : 0)   (= phi(16*sl + 8*q2 + j)).
// KIND 0: positional enc: d=f/20, scale from f%20, valid f<60
// KIND 1: view enc: d=3+f/8, scale from f%8, valid f<24
template <int KIND>
__device__ __forceinline__ bf16x8 trig_frag(const float (&x)[6], int q2, int sl) {
  bf16x8 r;
#pragma unroll
  for (int j = 0; j < 8; ++j) {
    const int kA = 16 * sl + j + (j >= 4 ? 4 : 0);  // q2 == 0 feature
    const int kB = kA + 4;                          // q2 == 1 feature
    int dA, dB; float scA, scB; bool vA, vB;
    if (KIND == 0) {
      vA = kA < 60; vB = kB < 60;
      dA = kA / 20; dB = kB / 20;
      scA = (float)(1 << ((kA % 20) >> 1)) * 0.5f;
      scB = (float)(1 << ((kB % 20) >> 1)) * 0.5f;
    } else {
      vA = kA < 24; vB = kB < 24;
      dA = 3 + (kA >> 3); dB = 3 + (kB >> 3);
      scA = (float)(1 << ((kA & 7) >> 1)) * 0.5f;
      scB = (float)(1 << ((kB & 7) >> 1)) * 0.5f;
    }
    float v  = q2 ? x[dB] : x[dA];
    float sc = q2 ? scB : scA;
    bool ok  = q2 ? vB : vA;
    float rev = v * sc;
    float t = (j & 1) ? __builtin_amdgcn_cosf(rev) : __builtin_amdgcn_sinf(rev);
    r[j] = (__bf16)(ok ? t : 0.0f);
  }
  return r;
}

// per-tile epilogue. t is a post-unroll constant at every call site.
template <bool RELU, int OUTM>
__device__ __forceinline__ void store_tile(int t, const floatx16& am0, const floatx16& am1,
                                           uint4 (&pout)[2][8], float* __restrict__ out,
                                           int q2, int pt0, int pt1) {
  if (OUTM == 2) {
    if (q2 == 0) {  // rgb = rows 0..2 -> regs 0..2 at q2==0
      float* o0 = out + (size_t)pt0 * 5;
      o0[0] = am0[0]; o0[1] = am0[1]; o0[2] = am0[2];
      float* o1 = out + (size_t)pt1 * 5;
      o1[0] = am1[0]; o1[1] = am1[1]; o1[2] = am1[2];
    }
  } else {
    if (OUTM == 0 || t < 4) {
#pragma unroll
      for (int gg = 0; gg < 4; ++gg) {
        float b0 = am0[4 * gg], b1 = am0[4 * gg + 1];
        float b2 = am0[4 * gg + 2], b3 = am0[4 * gg + 3];
        float c0 = am1[4 * gg], c1 = am1[4 * gg + 1];
        float c2 = am1[4 * gg + 2], c3 = am1[4 * gg + 3];
        if (RELU) {
          b0 = fmaxf(b0, 0.f); b1 = fmaxf(b1, 0.f);
          b2 = fmaxf(b2, 0.f); b3 = fmaxf(b3, 0.f);
          c0 = fmaxf(c0, 0.f); c1 = fmaxf(c1, 0.f);
          c2 = fmaxf(c2, 0.f); c3 = fmaxf(c3, 0.f);
        }
        if ((gg & 1) == 0) {
          pout[0][2 * t + (gg >> 1)].x = pk2(b0, b1);
          pout[0][2 * t + (gg >> 1)].y = pk2(b2, b3);
          pout[1][2 * t + (gg >> 1)].x = pk2(c0, c1);
          pout[1][2 * t + (gg >> 1)].y = pk2(c2, c3);
        } else {
          pout[0][2 * t + (gg >> 1)].z = pk2(b0, b1);
          pout[0][2 * t + (gg >> 1)].w = pk2(b2, b3);
          pout[1][2 * t + (gg >> 1)].z = pk2(c0, c1);
          pout[1][2 * t + (gg >> 1)].w = pk2(c2, c3);
        }
      }
    }
    if (OUTM == 1 && q2 == 0) {
      if (t == 0) {  // density = feature[:,0] = row 0 (f32, pre-rounding)
        out[(size_t)pt0 * 5 + 3] = am0[0];
        out[(size_t)pt1 * 5 + 3] = am1[0];
      }
      if (t == 4) {  // blending = sigmoid(row 128)
        out[(size_t)pt0 * 5 + 4] = 1.0f / (1.0f + __expf(-am0[0]));
        out[(size_t)pt1 * 5 + 4] = 1.0f / (1.0f + __expf(-am1[0]));
      }
    }
  }
}

// 32x32x16 bf16 MFMA, A = weights (m=feature), B = activations (n=point).
// Activations ping-pong between register banks pin/pout (uint4[2][8], feature
// order matching phi'd MFMA-B exactly -> B = bit_cast(pin[m][s]), zero build).
// r9: ROLLING A-PREFETCH WINDOW. r8's arithmetic showed per-wave MFMA duty =
// MfmaUtil = 43%: the 2 waves/SIMD (from different blocks, already barrier-
// independent) are phase-locked convoys — both stall in the same [load burst
// -> waitcnt -> MFMA burst] gaps (compiler left ~70 regs unused, VGPR 124:
// it did NOT pipeline across tile-groups). Fix: flatten (t,s) into one
// stream; keep DEPTH=6 A-frags in flight (24 VGPR); consume win[p], issue
// load for p+6 (6x64cyc = 384cyc cover > L2 ~250 / LDS ~120). Fully unrolled
// -> static window indices (rule #20). Otherwise bit-identical to r7.
// HYBRID A-sourcing unchanged: t<HT from 24 KiB LDS half; t>=HT from L2.
// S: k-steps. SL: k-steps from pin (rest from tail). NT: 32-feature tiles.
// HT: LDS tiles. PP: LDS parity. NB: staging bytes (compile-time).
// OUTM: 0=pack pout, 1=d2_3 (pack t<4 + density/blend), 2=c_1 (rgb only).
template <int S, int SL, int NT, int HT, int PP, bool RELU, int OUTM, int NB>
__device__ __forceinline__ void run_layer(const unsigned short* __restrict__ wsrc,
                                          const unsigned short* __restrict__ nsrc,
                                          unsigned short* __restrict__ sWt,
                                          const uint4 (&pin)[2][8],
                                          uint4 (&pout)[2][8],
                                          const bf16x8 (&tail)[2][4],
                                          floatx16 ZACC,
                                          float* __restrict__ out, int base, int tid) {
  const int lane = tid & 63;
  const int w = tid >> 6;
  const int q2 = lane >> 5;
  const int l31 = lane & 31;
  const int pt0 = base + w * 64 + l31;
  const int pt1 = pt0 + 32;

  __syncthreads();  // buf[PP] valid (staged a full layer ago); buf[PP^1] free

  // stage NEXT layer's LDS-half into buf[PP^1] (drains at the NEXT barrier)
  if (NB > 0) {
    const uint4* __restrict__ s4 = (const uint4*)nsrc;
    uint4* __restrict__ dst = (uint4*)(sWt + (PP ^ 1) * 12288);
#pragma unroll
    for (int kI = 0; kI < NB / (16 * 256); ++kI) {
      const int i = kI * 256 + tid;
      stage16(s4 + i, dst + (i & ~63));
    }
  }

  const unsigned short* __restrict__ ldsbuf = sWt + PP * 12288;
  const uint4* __restrict__ wp = (const uint4*)wsrc;

  auto loadA = [&](int p) -> bf16x8 {
    const int t = p / S, s = p % S;   // compile-time after full unroll
    if (t < HT) return *(const bf16x8*)&ldsbuf[(t * S + s) * 512 + lane * 8];
    return __builtin_bit_cast(bf16x8, wp[(t * S + s) * 64 + lane]);
  };

  constexpr int TOT = NT * S;
  constexpr int DEPTH = 6;  // 24 VGPR window
  bf16x8 win[DEPTH];

  // prologue: fill the window
#pragma unroll
  for (int p = 0; p < DEPTH && p < TOT; ++p) win[p] = loadA(p);

  floatx16 a0, a1;
#pragma unroll
  for (int p = 0; p < TOT; ++p) {
    const int t = p / S, s = p % S;
    bf16x8 A = win[p % DEPTH];                       // consume (waits only this slot)
    if (p + DEPTH < TOT) win[p % DEPTH] = loadA(p + DEPTH);  // refill slot
    bf16x8 B0 = (s < SL) ? __builtin_bit_cast(bf16x8, pin[0][(s < SL) ? s : 0])
                         : tail[0][s - SL];
    bf16x8 B1 = (s < SL) ? __builtin_bit_cast(bf16x8, pin[1][(s < SL) ? s : 0])
                         : tail[1][s - SL];
    if (s == 0) {
      a0 = __builtin_amdgcn_mfma_f32_32x32x16_bf16(A, B0, ZACC, 0, 0, 0);
      a1 = __builtin_amdgcn_mfma_f32_32x32x16_bf16(A, B1, ZACC, 0, 0, 0);
    } else {
      a0 = __builtin_amdgcn_mfma_f32_32x32x16_bf16(A, B0, a0, 0, 0, 0);
      a1 = __builtin_amdgcn_mfma_f32_32x32x16_bf16(A, B1, a1, 0, 0, 0);
    }
    if (s == S - 1)
      store_tile<RELU, OUTM>(t, a0, a1, pout, out, q2, pt0, pt1);
  }
}

// launch_bounds(256,2): the unique no-spill point (r2/r4: tighter caps spill
// 0.6-2.4 GB scratch). Live set with window: ~188 (r8 measured) + 24 window
// < 256 budget. If WRITE_SIZE balloons past ~25 MB the window spilled.
__global__ __launch_bounds__(256, 2) void nerf_main(const float* __restrict__ x,
                                                    const unsigned short* __restrict__ ws,
                                                    float* __restrict__ out) {
  __shared__ __align__(16) unsigned short sWt[2 * 12288];  // 2 x 24 KB ping-pong halves

  const int tid = (int)threadIdx.x;
  const int base = (int)blockIdx.x * 256;
  const int lane = tid & 63;
  const int w = tid >> 6;
  const int q2 = lane >> 5;
  const int l31 = lane & 31;
  const int pt0 = base + w * 64 + l31;

  // stage layer 0's LDS-half (tiles 0..1, 8 KB) into buf0 immediately
  {
    const uint4* s4 = (const uint4*)ws;
    uint4* dst = (uint4*)sWt;
#pragma unroll
    for (int i = 0; i < 2; ++i)
      stage16(s4 + i * 256 + tid, dst + ((i * 256 + tid) & ~63));
  }

  // per-lane x in registers (pt fixed per lane for whole kernel)
  float x0[6], x1[6];
  {
    const float* a = x + (size_t)pt0 * 6;
    const float* b = x + (size_t)(pt0 + 32) * 6;
#pragma unroll
    for (int c = 0; c < 3; ++c) {
      float2 u = *(const float2*)(a + 2 * c);
      float2 v = *(const float2*)(b + 2 * c);
      x0[2 * c] = u.x; x0[2 * c + 1] = u.y;
      x1[2 * c] = v.x; x1[2 * c + 1] = v.y;
    }
  }

  // positional trig frags computed ONCE (used by d1_0 and d2_0); overlaps staging
  bf16x8 pkt[2][4];
#pragma unroll
  for (int sl = 0; sl < 4; ++sl) {
    pkt[0][sl] = trig_frag<0>(x0, q2, sl);
    pkt[1][sl] = trig_frag<0>(x1, q2, sl);
  }

  // persistent zero accumulator (C of each tile's first MFMA)
  floatx16 zacc;
#pragma unroll
  for (int i = 0; i < 16; ++i) zacc[i] = 0.0f;

  // activation ping-pong register banks
  uint4 P0[2][8], P1[2][8];

  // Staging ledger (24K halves, r0/r7's proven hybrid):
  //   prologue->d1_0:8K(HT2)   d1_0->d1_1:16K(HT2)  d1_1->d1_2:16K(HT2)
  //   d1_2->d2_0:24K(HT2)      d2_0->d2_1:16K(HT2)  d2_1->d2_2:16K(HT2)
  //   d2_2->d2_3:24K(HT3)      d2_3->c_0:20K(HT2)   c_0->c_1:8K(HT1)
  //          S   SL NT HT PP relu  out NB       wsrc          next_src
  run_layer< 4, 0, 4, 2, 0, true , 0, 16384>(ws + 0u,      ws + 8192u,   sWt, P0, P0, pkt, zacc, out, base, tid); // d1_0 (in unused)
  run_layer< 8, 8, 4, 2, 1, true , 0, 16384>(ws + 8192u,   ws + 24576u,  sWt, P0, P1, pkt, zacc, out, base, tid); // d1_1
  run_layer< 8, 8, 4, 2, 0, false, 0, 24576>(ws + 24576u,  ws + 40960u,  sWt, P1, P0, pkt, zacc, out, base, tid); // d1_2 -> part1
  run_layer<12, 8, 4, 2, 1, true , 0, 16384>(ws + 40960u,  ws + 65536u,  sWt, P0, P1, pkt, zacc, out, base, tid); // d2_0 [part1|enc_pos]
  run_layer< 8, 8, 4, 2, 0, true , 0, 16384>(ws + 65536u,  ws + 81920u,  sWt, P1, P0, pkt, zacc, out, base, tid); // d2_1
  run_layer< 8, 8, 4, 2, 1, true , 0, 24576>(ws + 81920u,  ws + 98304u,  sWt, P0, P1, pkt, zacc, out, base, tid); // d2_2
  run_layer< 8, 8, 5, 3, 0, false, 1, 20480>(ws + 98304u,  ws + 118784u, sWt, P1, P0, pkt, zacc, out, base, tid); // d2_3

  // view trig frags (pkt regs dead after d2_0 -> reuse pressure window)
  // only [*][0..1] are ever read (c_0: S-SL = 2 tail steps)
  bf16x8 vw[2][4];
#pragma unroll
  for (int sl = 0; sl < 2; ++sl) {
    vw[0][sl] = trig_frag<1>(x0, q2, sl);
    vw[1][sl] = trig_frag<1>(x1, q2, sl);
  }
  vw[0][2] = vw[0][0]; vw[0][3] = vw[0][0];
  vw[1][2] = vw[1][0]; vw[1][3] = vw[1][0];

  run_layer<10, 8, 4, 2, 1, true , 0,  8192>(ws + 118784u, ws + 139264u, sWt, P0, P1, vw,  zacc, out, base, tid); // c_0 [feature|enc_view]
  run_layer< 8, 8, 1, 1, 0, false, 2,     0>(ws + 139264u, (const unsigned short*)nullptr, sWt, P1, P0, pkt, zacc, out, base, tid); // c_1 -> rgb
}

extern "C" void kernel_launch(void* const* d_in, const int* in_sizes, int n_in,
                              void* d_out, int out_size, void* d_ws, size_t ws_size,
                              hipStream_t stream) {
  (void)n_in; (void)out_size; (void)ws_size;
  const float* x = (const float*)d_in[0];
  SrcPtrs sp;
  for (int i = 0; i < 9; ++i) sp.p[i] = (const float*)d_in[1 + i];
  unsigned short* ws = (unsigned short*)d_ws;
  float* out = (float*)d_out;
  const int N = in_sizes[0] / 6;

  prep_zero<<<70, 256, 0, stream>>>(ws);
  prep_fill<<<144, 256, 0, stream>>>(sp, ws);
  nerf_main<<<N / 256, 256, 0, stream>>>(x, ws, out);
}

// Round 10
// 336.939 us; speedup vs baseline: 1.0372x; 1.0372x over previous
//
#include <hip/hip_runtime.h>
#include <cstdint>
#include <cstddef>

typedef __attribute__((ext_vector_type(8))) __bf16 bf16x8;
typedef __attribute__((ext_vector_type(16))) float floatx16;

struct SrcPtrs { const float* p[9]; };

// ---------------- weight workspace layout (bf16 elems) ----------------
// Frag-major per layer: frag f = t*S + s (t = 32-feature tile, s = 16-k step).
// Each frag = 1024 B = 64 lanes x 16 B; lane l = q2*32 + l31 holds
// row (32t + l31), k = 16s + 8*q2 + {0..7} — the 32x32x16 bf16 A layout.
// r7: the k index additionally carries the involution phi = swap bits 2,3 of
// (k & 15). With phi baked into the stored weights AND the trig feature
// mapping, the packed C-output registers of layer L are BIT-IDENTICAL to the
// B-fragments of layer L+1 -> no cross-lane half-swap, no B-build.
// m  mat    K    Nout  S   NT  off(shorts)  remap
// 0  Wd1_0  60   128   4   4   0
// 1  Wd1_1  128  128   8   4   8192
// 2  Wd1_2  128  128   8   4   24576
// 3  Wd2_0  188  128   12  4   40960    k<60 -> 128+k, k>=60 -> k-60
// 4  Wd2_1  128  128   8   4   65536
// 5  Wd2_2  128  128   8   4   81920
// 6  Wd2_3  128  129   8   5   98304    col0 -> row128 (blend), col j+1 -> row j
// 7  Wc_0   152  128   10  4   118784   k<24 -> 128+k, k>=24 -> k-24
// 8  Wc_1   128  3     8   1   139264   rows 3..31 zero
// total 143360 shorts = 286720 B

__global__ void prep_zero(unsigned short* __restrict__ ws) {
  uint4* p = (uint4*)ws;
  const int n = 143360 / 8;
  for (int i = blockIdx.x * blockDim.x + threadIdx.x; i < n; i += gridDim.x * blockDim.x)
    p[i] = make_uint4(0u, 0u, 0u, 0u);
}

__global__ void prep_fill(SrcPtrs sp, unsigned short* __restrict__ ws) {
  const int m  = blockIdx.x >> 4;
  const int sl = blockIdx.x & 15;
  const int K[9]  = {60, 128, 128, 188, 128, 128, 128, 152, 128};
  const int N[9]  = {128, 128, 128, 128, 128, 128, 129, 128, 3};
  const int SS[9] = {4, 8, 8, 12, 8, 8, 8, 10, 8};
  const unsigned OFF[9] = {0u, 8192u, 24576u, 40960u, 65536u, 81920u, 98304u, 118784u, 139264u};
  const int Km = K[m], Nm = N[m], Sm = SS[m];
  const float* __restrict__ src = sp.p[m];
  unsigned short* __restrict__ dst = ws + OFF[m];
  const int tot = Km * Nm;
  for (int i = sl * 256 + (int)threadIdx.x; i < tot; i += 16 * 256) {
    int k = i / Nm;
    int n = i - k * Nm;
    int kk = k, row = n;
    if (m == 3) kk = (k < 60) ? 128 + k : k - 60;
    if (m == 7) kk = (k < 24) ? 128 + k : k - 24;
    if (m == 6) row = (n == 0) ? 128 : n - 1;
    // phi: swap bits 2,3 of the k low nibble (involution). Makes packed
    // C-outputs feed MFMA-B directly (see header comment).
    kk = (kk & ~12) | (((kk & 4) << 1) | ((kk & 8) >> 1));
    const int t = row >> 5, l31 = row & 31;
    const int s = kk >> 4, q2 = (kk >> 3) & 1, j = kk & 7;
    dst[(t * Sm + s) * 512 + (q2 * 32 + l31) * 8 + j] =
        __builtin_bit_cast(unsigned short, (__bf16)src[i]);
  }
}

// ---------------- main fused kernel ----------------

__device__ __forceinline__ unsigned pk2(float a, float b) {
  unsigned short ua = __builtin_bit_cast(unsigned short, (__bf16)a);
  unsigned short ub = __builtin_bit_cast(unsigned short, (__bf16)b);
  return (unsigned)ua | ((unsigned)ub << 16);
}

__device__ __forceinline__ void stage16(const void* g, void* l) {
  __builtin_amdgcn_global_load_lds(
      (const __attribute__((address_space(1))) unsigned int*)g,
      (__attribute__((address_space(3))) unsigned int*)l, 16, 0, 0);
}

// sin/cos of v * pi * 2^f == sin/cos(2*pi*rev), rev = v * 2^(f-1) (HW revolutions)
// phi-adjusted feature mapping: lane q2, element j supplies feature
// f = 16*sl + j + 4*q2 + (j>=4 ? 4 : 0)   (= phi(16*sl + 8*q2 + j)).
// KIND 0: positional enc: d=f/20, scale from f%20, valid f<60
// KIND 1: view enc: d=3+f/8, scale from f%8, valid f<24
template <int KIND>
__device__ __forceinline__ bf16x8 trig_frag(const float (&x)[6], int q2, int sl) {
  bf16x8 r;
#pragma unroll
  for (int j = 0; j < 8; ++j) {
    const int kA = 16 * sl + j + (j >= 4 ? 4 : 0);  // q2 == 0 feature
    const int kB = kA + 4;                          // q2 == 1 feature
    int dA, dB; float scA, scB; bool vA, vB;
    if (KIND == 0) {
      vA = kA < 60; vB = kB < 60;
      dA = kA / 20; dB = kB / 20;
      scA = (float)(1 << ((kA % 20) >> 1)) * 0.5f;
      scB = (float)(1 << ((kB % 20) >> 1)) * 0.5f;
    } else {
      vA = kA < 24; vB = kB < 24;
      dA = 3 + (kA >> 3); dB = 3 + (kB >> 3);
      scA = (float)(1 << ((kA & 7) >> 1)) * 0.5f;
      scB = (float)(1 << ((kB & 7) >> 1)) * 0.5f;
    }
    float v  = q2 ? x[dB] : x[dA];
    float sc = q2 ? scB : scA;
    bool ok  = q2 ? vB : vA;
    float rev = v * sc;
    float t = (j & 1) ? __builtin_amdgcn_cosf(rev) : __builtin_amdgcn_sinf(rev);
    r[j] = (__bf16)(ok ? t : 0.0f);
  }
  return r;
}

// per-tile epilogue. t is a post-unroll constant at every call site.
template <bool RELU, int OUTM>
__device__ __forceinline__ void store_tile(int t, const floatx16& am0, const floatx16& am1,
                                           uint4 (&pout)[2][8], float* __restrict__ out,
                                           int q2, int pt0, int pt1) {
  if (OUTM == 2) {
    if (q2 == 0) {  // rgb = rows 0..2 -> regs 0..2 at q2==0
      float* o0 = out + (size_t)pt0 * 5;
      o0[0] = am0[0]; o0[1] = am0[1]; o0[2] = am0[2];
      float* o1 = out + (size_t)pt1 * 5;
      o1[0] = am1[0]; o1[1] = am1[1]; o1[2] = am1[2];
    }
  } else {
    if (OUTM == 0 || t < 4) {
#pragma unroll
      for (int gg = 0; gg < 4; ++gg) {
        float b0 = am0[4 * gg], b1 = am0[4 * gg + 1];
        float b2 = am0[4 * gg + 2], b3 = am0[4 * gg + 3];
        float c0 = am1[4 * gg], c1 = am1[4 * gg + 1];
        float c2 = am1[4 * gg + 2], c3 = am1[4 * gg + 3];
        if (RELU) {
          b0 = fmaxf(b0, 0.f); b1 = fmaxf(b1, 0.f);
          b2 = fmaxf(b2, 0.f); b3 = fmaxf(b3, 0.f);
          c0 = fmaxf(c0, 0.f); c1 = fmaxf(c1, 0.f);
          c2 = fmaxf(c2, 0.f); c3 = fmaxf(c3, 0.f);
        }
        if ((gg & 1) == 0) {
          pout[0][2 * t + (gg >> 1)].x = pk2(b0, b1);
          pout[0][2 * t + (gg >> 1)].y = pk2(b2, b3);
          pout[1][2 * t + (gg >> 1)].x = pk2(c0, c1);
          pout[1][2 * t + (gg >> 1)].y = pk2(c2, c3);
        } else {
          pout[0][2 * t + (gg >> 1)].z = pk2(b0, b1);
          pout[0][2 * t + (gg >> 1)].w = pk2(b2, b3);
          pout[1][2 * t + (gg >> 1)].z = pk2(c0, c1);
          pout[1][2 * t + (gg >> 1)].w = pk2(c2, c3);
        }
      }
    }
    if (OUTM == 1 && q2 == 0) {
      if (t == 0) {  // density = feature[:,0] = row 0 (f32, pre-rounding)
        out[(size_t)pt0 * 5 + 3] = am0[0];
        out[(size_t)pt1 * 5 + 3] = am1[0];
      }
      if (t == 4) {  // blending = sigmoid(row 128)
        out[(size_t)pt0 * 5 + 4] = 1.0f / (1.0f + __expf(-am0[0]));
        out[(size_t)pt1 * 5 + 4] = 1.0f / (1.0f + __expf(-am1[0]));
      }
    }
  }
}

// 32x32x16 bf16 MFMA, A = weights (m=feature), B = activations (n=point).
// Activations ping-pong between register banks pin/pout (uint4[2][8], feature
// order matching phi'd MFMA-B exactly -> B = bit_cast(pin[m][s]), zero build).
// r10: WINDOW + TILE-PAIR. r9's rolling window (A-latency cover) raised duty
// 43->51%; the residual gap matches dependent-MFMA issue latency on only 2
// accumulator chains (r8's 4-chain null was masked by A-latency, which the
// window has now removed). Pair tiles (t0,t1) per s-step: 4 independent
// chains a00,a01,a10,a11; window interleaves the pair's A-positions
// (DEPTH=8 slots = 4 s-steps ~= 512 cyc cover). Odd tail tiles (d2_3 t=4,
// all of c_1) use a batched-load prologue with 2 chains.
// HYBRID A-sourcing unchanged: t<HT from 24 KiB LDS half; t>=HT from L2.
// S: k-steps. SL: k-steps from pin (rest from tail). NT: 32-feature tiles.
// HT: LDS tiles. PP: LDS parity. NB: staging bytes (compile-time).
// OUTM: 0=pack pout, 1=d2_3 (pack t<4 + density/blend), 2=c_1 (rgb only).
template <int S, int SL, int NT, int HT, int PP, bool RELU, int OUTM, int NB>
__device__ __forceinline__ void run_layer(const unsigned short* __restrict__ wsrc,
                                          const unsigned short* __restrict__ nsrc,
                                          unsigned short* __restrict__ sWt,
                                          const uint4 (&pin)[2][8],
                                          uint4 (&pout)[2][8],
                                          const bf16x8 (&tail)[2][4],
                                          floatx16 ZACC,
                                          float* __restrict__ out, int base, int tid) {
  const int lane = tid & 63;
  const int w = tid >> 6;
  const int q2 = lane >> 5;
  const int l31 = lane & 31;
  const int pt0 = base + w * 64 + l31;
  const int pt1 = pt0 + 32;

  __syncthreads();  // buf[PP] valid (staged a full layer ago); buf[PP^1] free

  // stage NEXT layer's LDS-half into buf[PP^1] (drains at the NEXT barrier)
  if (NB > 0) {
    const uint4* __restrict__ s4 = (const uint4*)nsrc;
    uint4* __restrict__ dst = (uint4*)(sWt + (PP ^ 1) * 12288);
#pragma unroll
    for (int kI = 0; kI < NB / (16 * 256); ++kI) {
      const int i = kI * 256 + tid;
      stage16(s4 + i, dst + (i & ~63));
    }
  }

  const unsigned short* __restrict__ ldsbuf = sWt + PP * 12288;
  const uint4* __restrict__ wp = (const uint4*)wsrc;

  auto loadA = [&](int t, int s) -> bf16x8 {   // t,s compile-time after unroll
    if (t < HT) return *(const bf16x8*)&ldsbuf[(t * S + s) * 512 + lane * 8];
    return __builtin_bit_cast(bf16x8, wp[(t * S + s) * 64 + lane]);
  };
  // pair-interleaved position q: tp = q/(2S), s = (q%(2S))>>1, u = q&1, t = 2tp+u
  auto loadAq = [&](int q) -> bf16x8 {
    const int tp = q / (2 * S), r = q % (2 * S);
    return loadA(2 * tp + (r & 1), r >> 1);
  };

  constexpr int NP = NT / 2;          // full pairs
  constexpr int TOTQ = NP * 2 * S;    // windowed positions
  constexpr int DEPTH = 8;            // 32 VGPR window = 4 s-steps of cover
  bf16x8 win[DEPTH];

  // prologue: fill the window
#pragma unroll
  for (int q = 0; q < DEPTH && q < TOTQ; ++q) win[q] = loadAq(q);

  floatx16 a00, a01, a10, a11;
#pragma unroll
  for (int tp = 0; tp < NP; ++tp) {
#pragma unroll
    for (int s = 0; s < S; ++s) {
      const int q0 = tp * 2 * S + 2 * s;
      bf16x8 A0 = win[q0 % DEPTH];
      if (q0 + DEPTH < TOTQ) win[q0 % DEPTH] = loadAq(q0 + DEPTH);
      bf16x8 A1 = win[(q0 + 1) % DEPTH];
      if (q0 + 1 + DEPTH < TOTQ) win[(q0 + 1) % DEPTH] = loadAq(q0 + 1 + DEPTH);
      bf16x8 B0 = (s < SL) ? __builtin_bit_cast(bf16x8, pin[0][(s < SL) ? s : 0])
                           : tail[0][s - SL];
      bf16x8 B1 = (s < SL) ? __builtin_bit_cast(bf16x8, pin[1][(s < SL) ? s : 0])
                           : tail[1][s - SL];
      if (s == 0) {
        a00 = __builtin_amdgcn_mfma_f32_32x32x16_bf16(A0, B0, ZACC, 0, 0, 0);
        a01 = __builtin_amdgcn_mfma_f32_32x32x16_bf16(A0, B1, ZACC, 0, 0, 0);
        a10 = __builtin_amdgcn_mfma_f32_32x32x16_bf16(A1, B0, ZACC, 0, 0, 0);
        a11 = __builtin_amdgcn_mfma_f32_32x32x16_bf16(A1, B1, ZACC, 0, 0, 0);
      } else {
        a00 = __builtin_amdgcn_mfma_f32_32x32x16_bf16(A0, B0, a00, 0, 0, 0);
        a01 = __builtin_amdgcn_mfma_f32_32x32x16_bf16(A0, B1, a01, 0, 0, 0);
        a10 = __builtin_amdgcn_mfma_f32_32x32x16_bf16(A1, B0, a10, 0, 0, 0);
        a11 = __builtin_amdgcn_mfma_f32_32x32x16_bf16(A1, B1, a11, 0, 0, 0);
      }
    }
    store_tile<RELU, OUTM>(2 * tp, a00, a01, pout, out, q2, pt0, pt1);
    store_tile<RELU, OUTM>(2 * tp + 1, a10, a11, pout, out, q2, pt0, pt1);
  }

  // ---- odd tail tile (d2_3: t=4, c_1: t=0): batched loads, 2 chains ----
  if (NT & 1) {
    const int t = NT - 1;
    bf16x8 At[S];
#pragma unroll
    for (int s = 0; s < S; ++s) At[s] = loadA(t, s);
    floatx16 b0, b1;
#pragma unroll
    for (int s = 0; s < S; ++s) {
      bf16x8 B0 = (s < SL) ? __builtin_bit_cast(bf16x8, pin[0][(s < SL) ? s : 0])
                           : tail[0][s - SL];
      bf16x8 B1 = (s < SL) ? __builtin_bit_cast(bf16x8, pin[1][(s < SL) ? s : 0])
                           : tail[1][s - SL];
      if (s == 0) {
        b0 = __builtin_amdgcn_mfma_f32_32x32x16_bf16(At[s], B0, ZACC, 0, 0, 0);
        b1 = __builtin_amdgcn_mfma_f32_32x32x16_bf16(At[s], B1, ZACC, 0, 0, 0);
      } else {
        b0 = __builtin_amdgcn_mfma_f32_32x32x16_bf16(At[s], B0, b0, 0, 0, 0);
        b1 = __builtin_amdgcn_mfma_f32_32x32x16_bf16(At[s], B1, b1, 0, 0, 0);
      }
    }
    store_tile<RELU, OUTM>(t, b0, b1, pout, out, q2, pt0, pt1);
  }
}

// launch_bounds(256,2): the unique no-spill point (r2/r4: tighter caps spill
// 0.6-2.4 GB scratch). Live set: r9 measured ~160 unified; +32 acc (pairing)
// +8 window = ~200 < 256 budget. Spill tripwire: WRITE_SIZE >> 25 MB.
__global__ __launch_bounds__(256, 2) void nerf_main(const float* __restrict__ x,
                                                    const unsigned short* __restrict__ ws,
                                                    float* __restrict__ out) {
  __shared__ __align__(16) unsigned short sWt[2 * 12288];  // 2 x 24 KB ping-pong halves

  const int tid = (int)threadIdx.x;
  const int base = (int)blockIdx.x * 256;
  const int lane = tid & 63;
  const int w = tid >> 6;
  const int q2 = lane >> 5;
  const int l31 = lane & 31;
  const int pt0 = base + w * 64 + l31;

  // stage layer 0's LDS-half (tiles 0..1, 8 KB) into buf0 immediately
  {
    const uint4* s4 = (const uint4*)ws;
    uint4* dst = (uint4*)sWt;
#pragma unroll
    for (int i = 0; i < 2; ++i)
      stage16(s4 + i * 256 + tid, dst + ((i * 256 + tid) & ~63));
  }

  // per-lane x in registers (pt fixed per lane for whole kernel)
  float x0[6], x1[6];
  {
    const float* a = x + (size_t)pt0 * 6;
    const float* b = x + (size_t)(pt0 + 32) * 6;
#pragma unroll
    for (int c = 0; c < 3; ++c) {
      float2 u = *(const float2*)(a + 2 * c);
      float2 v = *(const float2*)(b + 2 * c);
      x0[2 * c] = u.x; x0[2 * c + 1] = u.y;
      x1[2 * c] = v.x; x1[2 * c + 1] = v.y;
    }
  }

  // positional trig frags computed ONCE (used by d1_0 and d2_0); overlaps staging
  bf16x8 pkt[2][4];
#pragma unroll
  for (int sl = 0; sl < 4; ++sl) {
    pkt[0][sl] = trig_frag<0>(x0, q2, sl);
    pkt[1][sl] = trig_frag<0>(x1, q2, sl);
  }

  // persistent zero accumulator (C of each tile's first MFMA)
  floatx16 zacc;
#pragma unroll
  for (int i = 0; i < 16; ++i) zacc[i] = 0.0f;

  // activation ping-pong register banks
  uint4 P0[2][8], P1[2][8];

  // Staging ledger (24K halves, r0/r7's proven hybrid):
  //   prologue->d1_0:8K(HT2)   d1_0->d1_1:16K(HT2)  d1_1->d1_2:16K(HT2)
  //   d1_2->d2_0:24K(HT2)      d2_0->d2_1:16K(HT2)  d2_1->d2_2:16K(HT2)
  //   d2_2->d2_3:24K(HT3)      d2_3->c_0:20K(HT2)   c_0->c_1:8K(HT1)
  //          S   SL NT HT PP relu  out NB       wsrc          next_src
  run_layer< 4, 0, 4, 2, 0, true , 0, 16384>(ws + 0u,      ws + 8192u,   sWt, P0, P0, pkt, zacc, out, base, tid); // d1_0 (in unused)
  run_layer< 8, 8, 4, 2, 1, true , 0, 16384>(ws + 8192u,   ws + 24576u,  sWt, P0, P1, pkt, zacc, out, base, tid); // d1_1
  run_layer< 8, 8, 4, 2, 0, false, 0, 24576>(ws + 24576u,  ws + 40960u,  sWt, P1, P0, pkt, zacc, out, base, tid); // d1_2 -> part1
  run_layer<12, 8, 4, 2, 1, true , 0, 16384>(ws + 40960u,  ws + 65536u,  sWt, P0, P1, pkt, zacc, out, base, tid); // d2_0 [part1|enc_pos]
  run_layer< 8, 8, 4, 2, 0, true , 0, 16384>(ws + 65536u,  ws + 81920u,  sWt, P1, P0, pkt, zacc, out, base, tid); // d2_1
  run_layer< 8, 8, 4, 2, 1, true , 0, 24576>(ws + 81920u,  ws + 98304u,  sWt, P0, P1, pkt, zacc, out, base, tid); // d2_2
  run_layer< 8, 8, 5, 3, 0, false, 1, 20480>(ws + 98304u,  ws + 118784u, sWt, P1, P0, pkt, zacc, out, base, tid); // d2_3

  // view trig frags (pkt regs dead after d2_0 -> reuse pressure window)
  // only [*][0..1] are ever read (c_0: S-SL = 2 tail steps)
  bf16x8 vw[2][4];
#pragma unroll
  for (int sl = 0; sl < 2; ++sl) {
    vw[0][sl] = trig_frag<1>(x0, q2, sl);
    vw[1][sl] = trig_frag<1>(x1, q2, sl);
  }
  vw[0][2] = vw[0][0]; vw[0][3] = vw[0][0];
  vw[1][2] = vw[1][0]; vw[1][3] = vw[1][0];

  run_layer<10, 8, 4, 2, 1, true , 0,  8192>(ws + 118784u, ws + 139264u, sWt, P0, P1, vw,  zacc, out, base, tid); // c_0 [feature|enc_view]
  run_layer< 8, 8, 1, 1, 0, false, 2,     0>(ws + 139264u, (const unsigned short*)nullptr, sWt, P1, P0, pkt, zacc, out, base, tid); // c_1 -> rgb
}

extern "C" void kernel_launch(void* const* d_in, const int* in_sizes, int n_in,
                              void* d_out, int out_size, void* d_ws, size_t ws_size,
                              hipStream_t stream) {
  (void)n_in; (void)out_size; (void)ws_size;
  const float* x = (const float*)d_in[0];
  SrcPtrs sp;
  for (int i = 0; i < 9; ++i) sp.p[i] = (const float*)d_in[1 + i];
  unsigned short* ws = (unsigned short*)d_ws;
  float* out = (float*)d_out;
  const int N = in_sizes[0] / 6;

  prep_zero<<<70, 256, 0, stream>>>(ws);
  prep_fill<<<144, 256, 0, stream>>>(sp, ws);
  nerf_main<<<N / 256, 256, 0, stream>>>(x, ws, out);
}